// Round 8
// baseline (56.030 us; speedup 1.0000x reference)
//
#include <hip/hip_runtime.h>
#include <hip/hip_bf16.h>
#include <math.h>

#define NFREQ 1024      // N_FFT//2
#define NMELS 256
#define NNOTES 82
#define KPAD  96        // K padded to multiple of 32 for mfma 16x16x32
#define KMAXH 400

typedef __attribute__((ext_vector_type(8))) short bf16x8;
typedef __attribute__((ext_vector_type(4))) float f32x4;

__device__ inline unsigned short f2bf(float x) {
    union { float f; unsigned int u; } c; c.f = x;
    unsigned int r = c.u + 0x7FFFu + ((c.u >> 16) & 1u);   // round-to-nearest-even
    return (unsigned short)(r >> 16);
}

// ------------- Kernel AB (merged): harmonic cols (LDS) -> mel -> log -> bf16 ----
__device__ inline double mel_to_hz_d(double m) {
    const double logstep = 0.06875177742094911;           // log(6.4)/27
    return (m >= 15.0) ? 1000.0 * exp(logstep * (m - 15.0)) : m * (200.0 / 3.0);
}

__global__ __launch_bounds__(256) void harm_prep(
    const float* __restrict__ omega,
    const float* __restrict__ stdv,
    const float* __restrict__ mask,
    unsigned short* __restrict__ wT)
{
    int n   = blockIdx.x;            // 0..95 (82..95 = K-pad rows)
    int tid = threadIdx.x;
    if (n >= NNOTES) {               // uniform per block: zero the pad column
        wT[tid * KPAD + n] = 0;
        return;
    }
    __shared__ float cols[NFREQ];

    // phase 1: cols[fi] = sum_k omega*mask*gauss for this note
    float f0 = 27.5f * exp2f((float)n / 12.0f);
    for (int fi = tid; fi < NFREQ; fi += 256) {
        float f = 11025.0f * (float)fi / 1023.0f;
        const float RAD = 80.0f;                           // 16*sigma at sigma=5
        int klo = (int)ceilf((f - RAD) / f0);
        int khi = (int)floorf((f + RAD) / f0);
        if (klo < 1) klo = 1;
        if (khi > KMAXH) khi = KMAXH;
        float acc = 0.0f;
        for (int k = klo; k <= khi; ++k) {
            int idx = n * KMAXH + (k - 1);
            float mk = mask[idx];
            if (mk == 0.0f) continue;
            float c = f0 * (float)k;
            float s = stdv[idx];
            float d = (f - c) / s;
            float e = 0.5f * d * d;
            if (e > 90.0f) continue;
            acc += omega[idx] * mk * expf(-e);
        }
        cols[fi] = acc;
    }
    __syncthreads();

    // phase 2: mel triangle m = tid over LDS cols, log-compress, bf16
    int m = tid;
    const double logstep = 0.06875177742094911;
    const double mel_max = 15.0 + log(11.025) / logstep;  // hz_to_mel(11025)
    double mf0 = mel_to_hz_d(mel_max * (double)m       / 257.0);
    double mf1 = mel_to_hz_d(mel_max * (double)(m + 1) / 257.0);
    double mf2 = mel_to_hz_d(mel_max * (double)(m + 2) / 257.0);
    double inv_lo = 1.0 / (mf1 - mf0);
    double inv_hi = 1.0 / (mf2 - mf1);
    double enorm  = 2.0 / (mf2 - mf0);
    int lo = (int)floor(mf0 * (1024.0 / 11025.0)) - 1;
    int hi = (int)ceil (mf2 * (1024.0 / 11025.0)) + 1;
    if (lo < 0) lo = 0;
    if (hi > 1023) hi = 1023;
    double acc = 0.0;
    for (int fi = lo; fi <= hi; ++fi) {
        double ff = 11025.0 * (double)(fi + 1) / 1024.0;
        double lower = (ff - mf0) * inv_lo;
        double upper = (mf2 - ff) * inv_hi;
        double wt = fmin(lower, upper);
        wt = fmax(0.0, wt) * enorm;
        acc += wt * (double)cols[fi];
    }
    float spec = (float)acc;
    const float X_MIN = -13.815510557964274f;             // log(1e-6)
    const float X_MAX = 3.0f;
    float x = logf(spec + 1e-6f);
    x = fminf(fmaxf(x, X_MIN), X_MAX);
    float wv = (x - X_MIN) * (1.0f / (X_MAX - X_MIN));
    wT[m * KPAD + n] = f2bf(wv);
}

// ---------------- Kernel C: out = y @ w, no LDS, no barriers --------------------
// Block: 64 rows x 256 cols, 4 waves (wave = 64 rows x 64 cols). Each lane's
// B-fragment is 8 consecutive floats of one y row -> load direct from global
// (4x float2, 8B-aligned), cvt_pk to bf16 in-register, MFMA. y tile is read by
// all 4 sister waves (L1-absorbed). k>=82 fragments are zero-predicated (w pad
// is zero anyway; avoids OOB reads past the exactly-page-sized y buffer).
__global__ __launch_bounds__(256) void harm_gemm(
    const float* __restrict__ y,
    const unsigned short* __restrict__ wT,
    float* __restrict__ out)
{
    int tid  = threadIdx.x;
    int lane = tid & 63;
    int wid  = tid >> 6;
    int r16  = lane & 15;
    int g4   = lane >> 4;
    int c0   = wid * 64;
    size_t m0 = (size_t)blockIdx.x * 64;

    // ---- 12 w fragments: block-invariant, L2-hot after first blocks ----
    bf16x8 bw[3][4];
    #pragma unroll
    for (int kb = 0; kb < 3; ++kb)
        #pragma unroll
        for (int c = 0; c < 4; ++c)
            bw[kb][c] = *(const bf16x8*)(wT + (size_t)(c0 + c * 16 + r16) * KPAD + kb * 32 + g4 * 8);

    #pragma unroll
    for (int i = 0; i < 4; ++i) {
        const float* yrow = y + (m0 + i * 16 + r16) * NNOTES + g4 * 8;

        // gather 3 fragments x 8 floats as predicated float2 loads
        float2 f[3][4];
        #pragma unroll
        for (int kb = 0; kb < 3; ++kb)
            #pragma unroll
            for (int q = 0; q < 4; ++q) {
                int k0 = kb * 32 + g4 * 8 + 2 * q;        // g4 is runtime
                f[kb][q] = (k0 < NNOTES)
                         ? *(const float2*)(yrow + kb * 32 + 2 * q)
                         : make_float2(0.f, 0.f);
            }

        f32x4 acc[4];
        #pragma unroll
        for (int c = 0; c < 4; ++c) acc[c] = (f32x4){0.f, 0.f, 0.f, 0.f};

        #pragma unroll
        for (int kb = 0; kb < 3; ++kb) {
            union { unsigned u[4]; bf16x8 v; } a;
            #pragma unroll
            for (int q = 0; q < 4; ++q) {
                unsigned pk;
                asm("v_cvt_pk_bf16_f32 %0, %1, %2" : "=v"(pk) : "v"(f[kb][q].x), "v"(f[kb][q].y));
                a.u[q] = pk;
            }
            #pragma unroll
            for (int c = 0; c < 4; ++c)
                acc[c] = __builtin_amdgcn_mfma_f32_16x16x32_bf16(bw[kb][c], a.v, acc[c], 0, 0, 0);
        }

        // lane holds out[row = m0+i*16+r16][col = c0 + c*16 + g4*4 + reg]
        float* orow = out + (m0 + i * 16 + r16) * NMELS + c0 + g4 * 4;
        #pragma unroll
        for (int c = 0; c < 4; ++c)
            *(f32x4*)(orow + c * 16) = acc[c];
    }
}

extern "C" void kernel_launch(void* const* d_in, const int* in_sizes, int n_in,
                              void* d_out, int out_size, void* d_ws, size_t ws_size,
                              hipStream_t stream) {
    const float* y     = (const float*)d_in[0];
    const float* omega = (const float*)d_in[1];
    const float* stdv  = (const float*)d_in[2];
    const float* mask  = (const float*)d_in[3];
    float* out = (float*)d_out;

    unsigned short* wT = (unsigned short*)d_ws;           // 256*96 bf16

    int R = in_sizes[0] / NNOTES;                         // 131072 rows

    harm_prep<<<KPAD, 256, 0, stream>>>(omega, stdv, mask, wT);
    harm_gemm<<<R / 64, 256, 0, stream>>>(y, wT, out);
}

// Round 9
// 49.040 us; speedup vs baseline: 1.1425x; 1.1425x over previous
//
#include <hip/hip_runtime.h>
#include <hip/hip_bf16.h>
#include <math.h>

#define NFREQ 1024      // N_FFT//2
#define NMELS 256
#define NNOTES 82
#define KPAD  96        // K padded to multiple of 32 for mfma 16x16x32
#define KMAXH 400

typedef __attribute__((ext_vector_type(8))) short bf16x8;
typedef __attribute__((ext_vector_type(4))) float f32x4;

__device__ inline unsigned short f2bf(float x) {
    union { float f; unsigned int u; } c; c.f = x;
    unsigned int r = c.u + 0x7FFFu + ((c.u >> 16) & 1u);   // round-to-nearest-even
    return (unsigned short)(r >> 16);
}

// ------------- Kernel AB (merged): harmonic cols (LDS) -> mel -> log -> bf16 ----
__device__ inline double mel_to_hz_d(double m) {
    const double logstep = 0.06875177742094911;           // log(6.4)/27
    return (m >= 15.0) ? 1000.0 * exp(logstep * (m - 15.0)) : m * (200.0 / 3.0);
}

__global__ __launch_bounds__(256) void harm_prep(
    const float* __restrict__ omega,
    const float* __restrict__ stdv,
    const float* __restrict__ mask,
    unsigned short* __restrict__ wT)
{
    int n   = blockIdx.x;            // 0..95 (82..95 = K-pad rows)
    int tid = threadIdx.x;
    if (n >= NNOTES) {               // uniform per block: zero the pad column
        wT[tid * KPAD + n] = 0;
        return;
    }
    __shared__ float cols[NFREQ];

    // phase 1: cols[fi] = sum_k omega*mask*gauss for this note
    float f0 = 27.5f * exp2f((float)n / 12.0f);
    for (int fi = tid; fi < NFREQ; fi += 256) {
        float f = 11025.0f * (float)fi / 1023.0f;
        const float RAD = 80.0f;                           // 16*sigma at sigma=5
        int klo = (int)ceilf((f - RAD) / f0);
        int khi = (int)floorf((f + RAD) / f0);
        if (klo < 1) klo = 1;
        if (khi > KMAXH) khi = KMAXH;
        float acc = 0.0f;
        for (int k = klo; k <= khi; ++k) {
            int idx = n * KMAXH + (k - 1);
            float mk = mask[idx];
            if (mk == 0.0f) continue;
            float c = f0 * (float)k;
            float s = stdv[idx];
            float d = (f - c) / s;
            float e = 0.5f * d * d;
            if (e > 90.0f) continue;
            acc += omega[idx] * mk * expf(-e);
        }
        cols[fi] = acc;
    }
    __syncthreads();

    // phase 2: mel triangle m = tid over LDS cols, log-compress, bf16
    int m = tid;
    const double logstep = 0.06875177742094911;
    const double mel_max = 15.0 + log(11.025) / logstep;  // hz_to_mel(11025)
    double mf0 = mel_to_hz_d(mel_max * (double)m       / 257.0);
    double mf1 = mel_to_hz_d(mel_max * (double)(m + 1) / 257.0);
    double mf2 = mel_to_hz_d(mel_max * (double)(m + 2) / 257.0);
    double inv_lo = 1.0 / (mf1 - mf0);
    double inv_hi = 1.0 / (mf2 - mf1);
    double enorm  = 2.0 / (mf2 - mf0);
    int lo = (int)floor(mf0 * (1024.0 / 11025.0)) - 1;
    int hi = (int)ceil (mf2 * (1024.0 / 11025.0)) + 1;
    if (lo < 0) lo = 0;
    if (hi > 1023) hi = 1023;
    double acc = 0.0;
    for (int fi = lo; fi <= hi; ++fi) {
        double ff = 11025.0 * (double)(fi + 1) / 1024.0;
        double lower = (ff - mf0) * inv_lo;
        double upper = (mf2 - ff) * inv_hi;
        double wt = fmin(lower, upper);
        wt = fmax(0.0, wt) * enorm;
        acc += wt * (double)cols[fi];
    }
    float spec = (float)acc;
    const float X_MIN = -13.815510557964274f;             // log(1e-6)
    const float X_MAX = 3.0f;
    float x = logf(spec + 1e-6f);
    x = fminf(fmaxf(x, X_MIN), X_MAX);
    float wv = (x - X_MIN) * (1.0f / (X_MAX - X_MIN));
    wT[m * KPAD + n] = f2bf(wv);
}

// ---------------- Kernel C: out = y @ w, occupancy-maximized ---------------------
// Single 64-row tile per block, grid 2048 (8 blocks/CU): cross-block TLP does
// the latency hiding. Single 13.3 KB LDS buffer; i-outer compute (acc = 16
// VGPR); bw loads issued after staging writes so v[] regs are dead (reused) and
// the L2 latency drains at the pre-barrier waitcnt. launch_bounds(256,6) caps
// VGPR at ~85 -> 6 waves/SIMD.
__global__ __launch_bounds__(256, 6) void harm_gemm(
    const float* __restrict__ y,
    const unsigned short* __restrict__ wT,
    float* __restrict__ out)
{
    __shared__ unsigned short ybf[64][104];   // 13.3 KB
    int tid = threadIdx.x;
    size_t m0 = (size_t)blockIdx.x * 64;

    // ---- stage y tile f32 -> bf16 (coalesced, 6-deep MLP) ----
    {
        const float4* ysrc = (const float4*)(y + m0 * NNOTES);  // 1312 float4
        float4 v[6];
        #pragma unroll
        for (int p = 0; p < 5; ++p) v[p] = ysrc[tid + 256 * p]; // j <= 1279 < 1312
        if (tid < 32) v[5] = ysrc[tid + 1280];
        #pragma unroll
        for (int p = 0; p < 6; ++p) {
            if (p < 5 || tid < 32) {
                int j  = tid + 256 * p;
                int e0 = 4 * j;                                // flat element index
                int e1 = e0 + 2;
                int r0 = (int)(((unsigned)e0 * 51151u) >> 22); // e0/82
                int r1 = (int)(((unsigned)e1 * 51151u) >> 22); // e1/82
                int c0e = e0 - 82 * r0;
                int c1e = e1 - 82 * r1;
                unsigned pk0, pk1;
                asm("v_cvt_pk_bf16_f32 %0, %1, %2" : "=v"(pk0) : "v"(v[p].x), "v"(v[p].y));
                asm("v_cvt_pk_bf16_f32 %0, %1, %2" : "=v"(pk1) : "v"(v[p].z), "v"(v[p].w));
                *(unsigned*)&ybf[r0][c0e] = pk0;
                *(unsigned*)&ybf[r1][c1e] = pk1;
            }
        }
        // zero K-pad cols 82..95: 64 rows x 7 u32
        for (int q = tid; q < 448; q += 256) {
            int r = (int)(((unsigned)q * 9363u) >> 16);        // q/7
            int c7 = q - 7 * r;
            *(unsigned*)&ybf[r][82 + 2 * c7] = 0u;
        }
    }

    int lane = tid & 63;
    int wid  = tid >> 6;
    int r16  = lane & 15;
    int g4   = lane >> 4;
    int c0   = wid * 64;

    // ---- 12 w fragments (issued after staging: v[] regs dead, L2 latency
    //      drains at the barrier's waitcnt) ----
    bf16x8 bw[3][4];
    #pragma unroll
    for (int kb = 0; kb < 3; ++kb)
        #pragma unroll
        for (int c = 0; c < 4; ++c)
            bw[kb][c] = *(const bf16x8*)(wT + (size_t)(c0 + c * 16 + r16) * KPAD + kb * 32 + g4 * 8);

    __syncthreads();

    #pragma unroll
    for (int i = 0; i < 4; ++i) {
        bf16x8 ay[3];
        #pragma unroll
        for (int kb = 0; kb < 3; ++kb)
            ay[kb] = *(const bf16x8*)&ybf[i * 16 + r16][kb * 32 + g4 * 8];

        f32x4 acc[4];
        #pragma unroll
        for (int c = 0; c < 4; ++c) acc[c] = (f32x4){0.f, 0.f, 0.f, 0.f};
        #pragma unroll
        for (int kb = 0; kb < 3; ++kb)
            #pragma unroll
            for (int c = 0; c < 4; ++c)
                acc[c] = __builtin_amdgcn_mfma_f32_16x16x32_bf16(bw[kb][c], ay[kb], acc[c], 0, 0, 0);

        // lane holds out[row = m0+i*16+r16][col = c0 + c*16 + g4*4 + reg]
        float* orow = out + (m0 + i * 16 + r16) * NMELS + c0 + g4 * 4;
        #pragma unroll
        for (int c = 0; c < 4; ++c)
            *(f32x4*)(orow + c * 16) = acc[c];
    }
}

extern "C" void kernel_launch(void* const* d_in, const int* in_sizes, int n_in,
                              void* d_out, int out_size, void* d_ws, size_t ws_size,
                              hipStream_t stream) {
    const float* y     = (const float*)d_in[0];
    const float* omega = (const float*)d_in[1];
    const float* stdv  = (const float*)d_in[2];
    const float* mask  = (const float*)d_in[3];
    float* out = (float*)d_out;

    unsigned short* wT = (unsigned short*)d_ws;           // 256*96 bf16

    int R = in_sizes[0] / NNOTES;                         // 131072 rows

    harm_prep<<<KPAD, 256, 0, stream>>>(omega, stdv, mask, wT);
    harm_gemm<<<R / 64, 256, 0, stream>>>(y, wT, out);
}

// Round 10
// 47.779 us; speedup vs baseline: 1.1727x; 1.0264x over previous
//
#include <hip/hip_runtime.h>
#include <hip/hip_bf16.h>
#include <math.h>

#define NFREQ 1024      // N_FFT//2
#define NMELS 256
#define NNOTES 82
#define KPAD  96        // K padded to multiple of 32 for mfma 16x16x32
#define KMAXH 400

typedef __attribute__((ext_vector_type(8))) short bf16x8;
typedef __attribute__((ext_vector_type(4))) float f32x4;

__device__ inline unsigned short f2bf(float x) {
    union { float f; unsigned int u; } c; c.f = x;
    unsigned int r = c.u + 0x7FFFu + ((c.u >> 16) & 1u);   // round-to-nearest-even
    return (unsigned short)(r >> 16);
}

// ------------- Kernel AB (merged): harmonic cols (LDS) -> mel -> log -> bf16 ----
__device__ inline double mel_to_hz_d(double m) {
    const double logstep = 0.06875177742094911;           // log(6.4)/27
    return (m >= 15.0) ? 1000.0 * exp(logstep * (m - 15.0)) : m * (200.0 / 3.0);
}

__global__ __launch_bounds__(256) void harm_prep(
    const float* __restrict__ omega,
    const float* __restrict__ stdv,
    const float* __restrict__ mask,
    unsigned short* __restrict__ wT)
{
    int n   = blockIdx.x;            // 0..95 (82..95 = K-pad rows)
    int tid = threadIdx.x;
    if (n >= NNOTES) {               // uniform per block: zero the pad column
        wT[tid * KPAD + n] = 0;      // (k>=82) x (garbage y bits) must give 0
        return;
    }
    __shared__ float cols[NFREQ];

    // phase 1: cols[fi] = sum_k omega*mask*gauss for this note
    float f0 = 27.5f * exp2f((float)n / 12.0f);
    for (int fi = tid; fi < NFREQ; fi += 256) {
        float f = 11025.0f * (float)fi / 1023.0f;
        const float RAD = 80.0f;                           // 16*sigma at sigma=5
        int klo = (int)ceilf((f - RAD) / f0);
        int khi = (int)floorf((f + RAD) / f0);
        if (klo < 1) klo = 1;
        if (khi > KMAXH) khi = KMAXH;
        float acc = 0.0f;
        for (int k = klo; k <= khi; ++k) {
            int idx = n * KMAXH + (k - 1);
            float mk = mask[idx];
            if (mk == 0.0f) continue;
            float c = f0 * (float)k;
            float s = stdv[idx];
            float d = (f - c) / s;
            float e = 0.5f * d * d;
            if (e > 90.0f) continue;
            acc += omega[idx] * mk * expf(-e);
        }
        cols[fi] = acc;
    }
    __syncthreads();

    // phase 2: mel triangle m = tid over LDS cols, log-compress, bf16
    int m = tid;
    const double logstep = 0.06875177742094911;
    const double mel_max = 15.0 + log(11.025) / logstep;  // hz_to_mel(11025)
    double mf0 = mel_to_hz_d(mel_max * (double)m       / 257.0);
    double mf1 = mel_to_hz_d(mel_max * (double)(m + 1) / 257.0);
    double mf2 = mel_to_hz_d(mel_max * (double)(m + 2) / 257.0);
    double inv_lo = 1.0 / (mf1 - mf0);
    double inv_hi = 1.0 / (mf2 - mf1);
    double enorm  = 2.0 / (mf2 - mf0);
    int lo = (int)floor(mf0 * (1024.0 / 11025.0)) - 1;
    int hi = (int)ceil (mf2 * (1024.0 / 11025.0)) + 1;
    if (lo < 0) lo = 0;
    if (hi > 1023) hi = 1023;
    double acc = 0.0;
    for (int fi = lo; fi <= hi; ++fi) {
        double ff = 11025.0 * (double)(fi + 1) / 1024.0;
        double lower = (ff - mf0) * inv_lo;
        double upper = (mf2 - ff) * inv_hi;
        double wt = fmin(lower, upper);
        wt = fmax(0.0, wt) * enorm;
        acc += wt * (double)cols[fi];
    }
    float spec = (float)acc;
    const float X_MIN = -13.815510557964274f;             // log(1e-6)
    const float X_MAX = 3.0f;
    float x = logf(spec + 1e-6f);
    x = fminf(fmaxf(x, X_MIN), X_MAX);
    float wv = (x - X_MIN) * (1.0f / (X_MAX - X_MIN));
    wT[m * KPAD + n] = f2bf(wv);
}

// ---------------- Kernel C: out = y @ w, global_load_lds staging ----------------
// Block: 64 rows x 256 cols, 4 waves (wave = 64 rows x 64 cols, split by col).
// y tile (64x82 f32, 20992 B contiguous) is DMA'd straight to LDS via 21
// wave-level global_load_lds dwordx4 calls (no VGPR round trip, no cvt/ds_write
// chain). f32 -> bf16 conversion happens at fragment-read time. Fragments whose
// k >= 82 read neighboring-row data / zeroed tail -> multiplied by zero wT rows.
__device__ __forceinline__ void gload16(const void* g, void* l) {
    __builtin_amdgcn_global_load_lds(
        (const __attribute__((address_space(1))) unsigned int*)g,
        (__attribute__((address_space(3))) unsigned int*)l, 16, 0, 0);
}

__global__ __launch_bounds__(256) void harm_gemm(
    const float* __restrict__ y,
    const unsigned short* __restrict__ wT,
    float* __restrict__ out)
{
    __shared__ float yf[5264];                 // 64*82 = 5248 f32 + 16 zero tail
    int tid  = threadIdx.x;
    int lane = tid & 63;
    int wid  = tid >> 6;
    int r16  = lane & 15;
    int g4   = lane >> 4;
    int c0   = wid * 64;
    size_t m0 = (size_t)blockIdx.x * 64;

    // zero the overrun tail (read by row-63 pad fragments; x0 in MFMA but must
    // be finite)
    if (tid < 16) yf[5248 + tid] = 0.0f;

    // ---- 12 w fragments (L2-hot); latency drains at the barrier ----
    bf16x8 bw[3][4];
    #pragma unroll
    for (int kb = 0; kb < 3; ++kb)
        #pragma unroll
        for (int c = 0; c < 4; ++c)
            bw[kb][c] = *(const bf16x8*)(wT + (size_t)(c0 + c * 16 + r16) * KPAD + kb * 32 + g4 * 8);

    // ---- DMA y tile to LDS: 21 wave-calls of 1024 B, round-robin over waves --
    {
        const float* ybase = y + m0 * NNOTES;              // 20992 B contiguous
        for (int c = wid; c < 21; c += 4) {
            int unit = c * 64 + lane;                      // 16B units, 1312 total
            if (unit < 1312)
                gload16(ybase + 4 * (size_t)unit, &yf[c * 256]);
        }
    }
    __syncthreads();   // drains vmcnt (gload_lds + bw) and lgkmcnt (tail zeros)

    #pragma unroll
    for (int i = 0; i < 4; ++i) {
        // fragment: 8 consecutive f32 of row i*16+r16 at k = kb*32 + g4*8,
        // cvt_pk'd to bf16x8 (8B-aligned ds reads; rows stride 328 B)
        bf16x8 ay[3];
        #pragma unroll
        for (int kb = 0; kb < 3; ++kb) {
            const float* fr = &yf[(i * 16 + r16) * NNOTES + kb * 32 + g4 * 8];
            float2 a0 = *(const float2*)(fr + 0);
            float2 a1 = *(const float2*)(fr + 2);
            float2 a2 = *(const float2*)(fr + 4);
            float2 a3 = *(const float2*)(fr + 6);
            union { unsigned u[4]; bf16x8 v; } A;
            asm("v_cvt_pk_bf16_f32 %0, %1, %2" : "=v"(A.u[0]) : "v"(a0.x), "v"(a0.y));
            asm("v_cvt_pk_bf16_f32 %0, %1, %2" : "=v"(A.u[1]) : "v"(a1.x), "v"(a1.y));
            asm("v_cvt_pk_bf16_f32 %0, %1, %2" : "=v"(A.u[2]) : "v"(a2.x), "v"(a2.y));
            asm("v_cvt_pk_bf16_f32 %0, %1, %2" : "=v"(A.u[3]) : "v"(a3.x), "v"(a3.y));
            ay[kb] = A.v;
        }

        f32x4 acc[4];
        #pragma unroll
        for (int c = 0; c < 4; ++c) acc[c] = (f32x4){0.f, 0.f, 0.f, 0.f};
        #pragma unroll
        for (int kb = 0; kb < 3; ++kb)
            #pragma unroll
            for (int c = 0; c < 4; ++c)
                acc[c] = __builtin_amdgcn_mfma_f32_16x16x32_bf16(bw[kb][c], ay[kb], acc[c], 0, 0, 0);

        // lane holds out[row = m0+i*16+r16][col = c0 + c*16 + g4*4 + reg]
        float* orow = out + (m0 + i * 16 + r16) * NMELS + c0 + g4 * 4;
        #pragma unroll
        for (int c = 0; c < 4; ++c)
            *(f32x4*)(orow + c * 16) = acc[c];
    }
}

extern "C" void kernel_launch(void* const* d_in, const int* in_sizes, int n_in,
                              void* d_out, int out_size, void* d_ws, size_t ws_size,
                              hipStream_t stream) {
    const float* y     = (const float*)d_in[0];
    const float* omega = (const float*)d_in[1];
    const float* stdv  = (const float*)d_in[2];
    const float* mask  = (const float*)d_in[3];
    float* out = (float*)d_out;

    unsigned short* wT = (unsigned short*)d_ws;           // 256*96 bf16

    int R = in_sizes[0] / NNOTES;                         // 131072 rows

    harm_prep<<<KPAD, 256, 0, stream>>>(omega, stdv, mask, wT);
    harm_gemm<<<R / 64, 256, 0, stream>>>(y, wT, out);
}